// Round 6
// baseline (259.637 us; speedup 1.0000x reference)
//
#include <hip/hip_runtime.h>

#define NB 16384
#define NDOM 10
#define HIDN 512
#define STYLE 64
#define NWIN 256   // NB / 64

typedef short bf16x8 __attribute__((ext_vector_type(8)));
typedef float f32x16 __attribute__((ext_vector_type(16)));

#define MFMA __builtin_amdgcn_mfma_f32_32x32x16_bf16

// ---------------- bf16 helpers ----------------

__device__ __forceinline__ unsigned bfr_hi(float x) {
    unsigned u = __float_as_uint(x);
    return (u + 0x7fffu + ((u >> 16) & 1u)) & 0xffff0000u;  // RNE bf16 in high bits
}

__device__ __forceinline__ unsigned cvtpk(float a, float b) {
    unsigned r;
    asm("v_cvt_pk_bf16_f32 %0, %1, %2" : "=v"(r) : "v"(a), "v"(b));
    return r;   // [15:0]=bf16(a), [31:16]=bf16(b)
}

__device__ __forceinline__ void cvhalf2(const float4& x, const float4& y, uint4& h, uint4& l) {
    float xs[8] = {x.x, x.y, x.z, x.w, y.x, y.y, y.z, y.w};
    unsigned hh[8], ll[8];
#pragma unroll
    for (int i = 0; i < 8; ++i) {
        unsigned hb = bfr_hi(xs[i]);
        hh[i] = hb;
        ll[i] = bfr_hi(xs[i] - __uint_as_float(hb));
    }
    h = make_uint4((hh[0] >> 16) | (hh[1] & 0xffff0000u), (hh[2] >> 16) | (hh[3] & 0xffff0000u),
                   (hh[4] >> 16) | (hh[5] & 0xffff0000u), (hh[6] >> 16) | (hh[7] & 0xffff0000u));
    l = make_uint4((ll[0] >> 16) | (ll[1] & 0xffff0000u), (ll[2] >> 16) | (ll[3] & 0xffff0000u),
                   (ll[4] >> 16) | (ll[5] & 0xffff0000u), (ll[6] >> 16) | (ll[7] & 0xffff0000u));
}

// ---------------- bucketing ----------------

__global__ void k_hist(const int* __restrict__ y, int* __restrict__ counts) {
    int b = blockIdx.x * 256 + threadIdx.x;   // grid 64
    int d = y[b];
    int lane = threadIdx.x & 63;
#pragma unroll
    for (int dd = 0; dd < NDOM; ++dd) {
        unsigned long long bal = __ballot(d == dd);
        if (bal != 0ULL && d == dd && lane == __builtin_ctzll(bal))
            atomicAdd(&counts[dd], (int)__popcll(bal));
    }
}

__global__ void k_scatter(const int* __restrict__ y, const int* __restrict__ counts,
                          int* __restrict__ cursors, int* __restrict__ rowidx) {
    __shared__ int soff[NDOM];
    if (threadIdx.x == 0) {
        int s = 0;
        for (int dd = 0; dd < NDOM; ++dd) { soff[dd] = s; s += counts[dd]; }
    }
    __syncthreads();
    int b = blockIdx.x * 256 + threadIdx.x;   // grid 64
    int d = y[b];
    int lane = threadIdx.x & 63;
#pragma unroll
    for (int dd = 0; dd < NDOM; ++dd) {
        unsigned long long bal = __ballot(d == dd);
        if (bal == 0ULL) continue;
        int leader = __builtin_ctzll(bal);
        int base = 0;
        if (d == dd && lane == leader)
            base = atomicAdd(&cursors[dd], (int)__popcll(bal));
        base = __shfl(base, leader);
        if (d == dd) {
            int rank = (int)__popcll(bal & ((1ULL << lane) - 1ULL));
            rowidx[soff[dd] + base + rank] = b;
        }
    }
}

// ---------------- weight prep (single bf16, frag-linear) -------------------
// Big mats (512x512): per (mat, w) block of 32768 shorts:
//   addr = ks*1024 + of*512 + k8*256 + c5*8 + j ; k = ks*16+k8*8+j, col = w*64+of*32+c5
// mats: 0..2 = W1..W3 ; 3+d = Wu1[d] ; 13+d = Wu2[d] ; 23+d = Wu3[d]
// W0 (16x512): granule g: w=g>>7, of=(g>>6)&1, k8=(g>>5)&1, c5=g&31 at W0p+g*8
// Wo (per dom 512x64): granule g: w1=g>>11, ks=(g>>6)&31, k8=(g>>5)&1, c5=g&31

__global__ void k_prep(const float* __restrict__ W1, const float* __restrict__ W2,
                       const float* __restrict__ W3, const float* __restrict__ Wu1,
                       const float* __restrict__ Wu2, const float* __restrict__ Wu3,
                       const float* __restrict__ W0, const float* __restrict__ Wo,
                       short* __restrict__ Wp, short* __restrict__ W0p,
                       short* __restrict__ WoP)
{
    const int b = blockIdx.x;
    const int t = threadIdx.x;
    if (b < 528) {
        __shared__ float Ld[64][66];
        const int mat = b >> 4, w = (b >> 1) & 7, sh = b & 1;
        const float* src;
        if (mat < 3) src = (mat == 0 ? W1 : (mat == 1 ? W2 : W3));
        else {
            int g = (mat - 3) / 10, d = (mat - 3) % 10;
            src = (g == 0 ? Wu1 : (g == 1 ? Wu2 : Wu3)) + (size_t)d * HIDN * HIDN;
        }
        short* dst = Wp + (size_t)mat * 262144 + w * 32768;
        for (int s = sh * 4; s < sh * 4 + 4; ++s) {
            __syncthreads();
            const int r4 = t >> 6, c = t & 63;
#pragma unroll
            for (int p = 0; p < 16; ++p) {
                int k = s * 64 + p * 4 + r4;
                Ld[p * 4 + r4][c] = src[(size_t)k * HIDN + w * 64 + c];
            }
            __syncthreads();
#pragma unroll
            for (int i = 0; i < 2; ++i) {
                int g = i * 256 + t;
                int ksl = g >> 7, of = (g >> 6) & 1, k8 = (g >> 5) & 1, c5 = g & 31;
                int kk = ksl * 16 + k8 * 8;
                unsigned pk[4];
#pragma unroll
                for (int j2 = 0; j2 < 4; ++j2) {
                    unsigned h0 = bfr_hi(Ld[kk + 2 * j2][of * 32 + c5]);
                    unsigned h1 = bfr_hi(Ld[kk + 2 * j2 + 1][of * 32 + c5]);
                    pk[j2] = (h0 >> 16) | (h1 & 0xffff0000u);
                }
                int ksg = s * 4 + ksl;
                *(uint4*)(dst + ksg * 1024 + of * 512 + k8 * 256 + c5 * 8) =
                    make_uint4(pk[0], pk[1], pk[2], pk[3]);
            }
        }
    } else if (b == 528) {
#pragma unroll
        for (int i = 0; i < 4; ++i) {
            int g = i * 256 + t;   // 1024 granules
            int w = g >> 7, of = (g >> 6) & 1, k8 = (g >> 5) & 1, c5 = g & 31;
            int col = w * 64 + of * 32 + c5;
            unsigned pk[4];
#pragma unroll
            for (int j2 = 0; j2 < 4; ++j2) {
                unsigned h0 = bfr_hi(W0[(size_t)(k8 * 8 + 2 * j2) * HIDN + col]);
                unsigned h1 = bfr_hi(W0[(size_t)(k8 * 8 + 2 * j2 + 1) * HIDN + col]);
                pk[j2] = (h0 >> 16) | (h1 & 0xffff0000u);
            }
            *(uint4*)(W0p + g * 8) = make_uint4(pk[0], pk[1], pk[2], pk[3]);
        }
    } else {
        const int dom = b - 529;
        const float* src = Wo + (size_t)dom * HIDN * STYLE;
        short* dst = WoP + (size_t)dom * 32768;
#pragma unroll
        for (int i = 0; i < 16; ++i) {
            int g = i * 256 + t;   // 4096 granules
            int w1 = g >> 11, ks = (g >> 6) & 31, k8 = (g >> 5) & 1, c5 = g & 31;
            int col = w1 * 32 + c5;
            int k0 = ks * 16 + k8 * 8;
            unsigned pk[4];
#pragma unroll
            for (int j2 = 0; j2 < 4; ++j2) {
                unsigned h0 = bfr_hi(src[(size_t)(k0 + 2 * j2) * STYLE + col]);
                unsigned h1 = bfr_hi(src[(size_t)(k0 + 2 * j2 + 1) * STYLE + col]);
                pk[j2] = (h0 >> 16) | (h1 & 0xffff0000u);
            }
            *(uint4*)(dst + g * 8) = make_uint4(pk[0], pk[1], pk[2], pk[3]);
        }
    }
}

// ---------------- fused persistent kernel ----------------
// 256 blocks x 512 threads (8 waves), block = 64 sorted rows.
// h in LDS: octet o=k>>3, line idx = o*512 + row*8 (shorts), 16B/line.
// Operand-swapped MFMA: A = weights (m=outcol), B = activations (n=batchrow).
// Wave w owns outcols [64w,64w+64) (of=2); nf=2 batchrow groups of 32.
// Weight prefetch ring depth 4; h-frags software-pipelined 1 ks ahead.

template<int NFM, bool BLO>
__device__ __forceinline__ void pass512(const short* __restrict__ sH,
                                        const short* __restrict__ sL,
                                        const short* __restrict__ pW, int lane,
                                        f32x16 ah[2][2], f32x16 al[2][2])
{
#pragma unroll
    for (int of = 0; of < 2; ++of)
#pragma unroll
        for (int nf = 0; nf < 2; ++nf)
            if (NFM & (1 << nf)) {
#pragma unroll
                for (int e = 0; e < 16; ++e) ah[of][nf][e] = 0.f;
                if (BLO)
#pragma unroll
                    for (int e = 0; e < 16; ++e) al[of][nf][e] = 0.f;
            }
    const short* pWl = pW + lane * 8;
    const int rb = (lane & 31) * 8;
    const int lh = lane >> 5;
    // weight ring, depth 4 (8 dwordx4 loads in flight)
    bf16x8 wv[4][2];
#pragma unroll
    for (int d = 0; d < 4; ++d) {
        wv[d][0] = *(const bf16x8*)(pWl + d * 1024);
        wv[d][1] = *(const bf16x8*)(pWl + d * 1024 + 512);
    }
    // h-frag double buffer (read 1 ks ahead)
    bf16x8 hb[2][2], lb[2][2];
    const int base0 = lh * 512 + rb;
#pragma unroll
    for (int nf = 0; nf < 2; ++nf)
        if (NFM & (1 << nf)) {
            hb[0][nf] = *(const bf16x8*)(sH + base0 + nf * 256);
            if (BLO) lb[0][nf] = *(const bf16x8*)(sL + base0 + nf * 256);
        }
#pragma unroll
    for (int ks = 0; ks < 32; ++ks) {
        const int pc = ks & 1, pn = pc ^ 1;
        bf16x8 w0 = wv[ks & 3][0], w1 = wv[ks & 3][1];
        if (ks < 28) {
            wv[ks & 3][0] = *(const bf16x8*)(pWl + (ks + 4) * 1024);
            wv[ks & 3][1] = *(const bf16x8*)(pWl + (ks + 4) * 1024 + 512);
        }
        if (ks < 31) {
            const int basen = (2 * (ks + 1) + lh) * 512 + rb;
#pragma unroll
            for (int nf = 0; nf < 2; ++nf)
                if (NFM & (1 << nf)) {
                    hb[pn][nf] = *(const bf16x8*)(sH + basen + nf * 256);
                    if (BLO) lb[pn][nf] = *(const bf16x8*)(sL + basen + nf * 256);
                }
        }
#pragma unroll
        for (int nf = 0; nf < 2; ++nf) {
            if (!(NFM & (1 << nf))) continue;
            ah[0][nf] = MFMA(w0, hb[pc][nf], ah[0][nf], 0, 0, 0);
            ah[1][nf] = MFMA(w1, hb[pc][nf], ah[1][nf], 0, 0, 0);
            if (BLO) {
                al[0][nf] = MFMA(w0, lb[pc][nf], al[0][nf], 0, 0, 0);
                al[1][nf] = MFMA(w1, lb[pc][nf], al[1][nf], 0, 0, 0);
            }
        }
    }
}

// epilogue: merge accs + bias (+ReLU), pack bf16 hi(/lo), shuffle-repack so each
// half-wave writes full contiguous 16B lines (conflict-free ds_write_b128).
template<bool BLO, bool WLO, bool RELU>
__device__ __forceinline__ void epi512(short* __restrict__ sH, short* __restrict__ sL,
                                       f32x16 ah[2][2], f32x16 al[2][2],
                                       const float* __restrict__ bias,
                                       int w, int lane, int rlo, int rhi)
{
    const int lh = lane >> 5;
#pragma unroll
    for (int nf = 0; nf < 2; ++nf) {
        const int row = nf * 32 + (lane & 31);
        const bool pred = (row >= rlo && row < rhi);
#pragma unroll
        for (int of = 0; of < 2; ++of) {
            unsigned mh[4][2], ml[4][2];
#pragma unroll
            for (int q = 0; q < 4; ++q) {
                // my 4 k-values: k = of*32 + q*8 + lh*4 + j
                float v[4];
#pragma unroll
                for (int j = 0; j < 4; ++j) {
                    float x = ah[of][nf][q * 4 + j];
                    if (BLO) x += al[of][nf][q * 4 + j];
                    x += bias[w * 64 + of * 32 + q * 8 + lh * 4 + j];
                    if (RELU) x = fmaxf(x, 0.f);
                    v[j] = x;
                }
                mh[q][0] = cvtpk(v[0], v[1]);
                mh[q][1] = cvtpk(v[2], v[3]);
                if (WLO) {
                    float l0 = v[0] - __uint_as_float(mh[q][0] << 16);
                    float l1 = v[1] - __uint_as_float(mh[q][0] & 0xffff0000u);
                    float l2 = v[2] - __uint_as_float(mh[q][1] << 16);
                    float l3 = v[3] - __uint_as_float(mh[q][1] & 0xffff0000u);
                    ml[q][0] = cvtpk(l0, l1);
                    ml[q][1] = cvtpk(l2, l3);
                }
            }
            // exchange with lane^32 (same row, other half of each 16B line);
            // lane writes full lines for q = 2t + lh  -> contiguous per half-wave
#pragma unroll
            for (int t = 0; t < 2; ++t) {
                const int q = 2 * t + lh;
                const int qs = 2 * t + (lh ^ 1);
                unsigned r0 = (unsigned)__shfl_xor((int)mh[qs][0], 32);
                unsigned r1 = (unsigned)__shfl_xor((int)mh[qs][1], 32);
                uint4 line = lh == 0 ? make_uint4(mh[q][0], mh[q][1], r0, r1)
                                     : make_uint4(r0, r1, mh[q][0], mh[q][1]);
                const int o = w * 8 + of * 4 + q;
                if (pred) *(uint4*)(sH + o * 512 + row * 8) = line;
                if (WLO) {
                    unsigned s0 = (unsigned)__shfl_xor((int)ml[qs][0], 32);
                    unsigned s1 = (unsigned)__shfl_xor((int)ml[qs][1], 32);
                    uint4 lin2 = lh == 0 ? make_uint4(ml[q][0], ml[q][1], s0, s1)
                                         : make_uint4(s0, s1, ml[q][0], ml[q][1]);
                    if (pred) *(uint4*)(sL + o * 512 + row * 8) = lin2;
                }
            }
        }
    }
}

__global__ __launch_bounds__(512, 2)
void k_fused(const float* __restrict__ z, const int* __restrict__ rowidx,
             const int* __restrict__ counts,
             const short* __restrict__ Wp, const short* __restrict__ W0p,
             const short* __restrict__ WoP,
             const float* __restrict__ b0, const float* __restrict__ b1,
             const float* __restrict__ b2, const float* __restrict__ b3,
             const float* __restrict__ bu1, const float* __restrict__ bu2,
             const float* __restrict__ bu3, const float* __restrict__ bo,
             float* __restrict__ out)
{
    __shared__ short sH[32768];   // 64 KiB  (h hi)
    __shared__ short sL[32768];   // 64 KiB  (h lo; valid from layer-3 output on)
    __shared__ int soff[NDOM + 1];

    // XCD-chunked bijective swizzle: neighbors share a domain -> L2 reuse
    const int win = (blockIdx.x & 7) * 32 + (blockIdx.x >> 3);
    const int row0 = win * 64;
    const int tid = threadIdx.x;
    const int lane = tid & 63;
    const int w = tid >> 6;
    const int lh = lane >> 5;

    if (tid == 0) {
        int s = 0;
#pragma unroll
        for (int dd = 0; dd < NDOM; ++dd) { soff[dd] = s; s += counts[dd]; }
        soff[NDOM] = s;
    }

    f32x16 ah[2][2], al[2][2];

    // ---- layer 0: z (K=16) -> h (hi-only out; z itself split hi/lo) ----
    {
#pragma unroll
        for (int a = 0; a < 2; ++a)
#pragma unroll
            for (int b = 0; b < 2; ++b)
#pragma unroll
                for (int e = 0; e < 16; ++e) { ah[a][b][e] = 0.f; al[a][b][e] = 0.f; }
        const short* pw0 = W0p + w * 1024 + lane * 8;
        bf16x8 w0 = *(const bf16x8*)(pw0);
        bf16x8 w1 = *(const bf16x8*)(pw0 + 512);
#pragma unroll
        for (int nf = 0; nf < 2; ++nf) {
            int r = nf * 32 + (lane & 31);
            int src = rowidx[row0 + r];
            const float* zp = z + (size_t)src * 16 + lh * 8;
            float4 f0 = *(const float4*)zp;
            float4 f1 = *(const float4*)(zp + 4);
            uint4 h, l;
            cvhalf2(f0, f1, h, l);
            bf16x8 zh = *(bf16x8*)&h;
            bf16x8 zl = *(bf16x8*)&l;
            ah[0][nf] = MFMA(w0, zh, ah[0][nf], 0, 0, 0);
            ah[1][nf] = MFMA(w1, zh, ah[1][nf], 0, 0, 0);
            al[0][nf] = MFMA(w0, zl, al[0][nf], 0, 0, 0);
            al[1][nf] = MFMA(w1, zl, al[1][nf], 0, 0, 0);
        }
        // fold z-lo contribution into hi acc, then write hi-only
#pragma unroll
        for (int a = 0; a < 2; ++a)
#pragma unroll
            for (int b = 0; b < 2; ++b)
#pragma unroll
                for (int e = 0; e < 16; ++e) ah[a][b][e] += al[a][b][e];
        epi512<false, false, true>(sH, sL, ah, al, b0, w, lane, 0, 64);
        __syncthreads();
    }

    // ---- trunk layers 1-3 (h hi-only inputs; layer 3 writes hi+lo) ----
#pragma unroll 1
    for (int m = 0; m < 3; ++m) {
        const float* bp = (m == 0) ? b1 : (m == 1) ? b2 : b3;
        pass512<3, false>(sH, sL, Wp + (size_t)m * 262144 + w * 32768, lane, ah, al);
        __syncthreads();
        if (m < 2) epi512<false, false, true>(sH, sL, ah, al, bp, w, lane, 0, 64);
        else       epi512<false, true,  true>(sH, sL, ah, al, bp, w, lane, 0, 64);
        __syncthreads();
    }

    // ---- head layers: per-domain, nf-granular (32-row groups) ----
#pragma unroll 1
    for (int L = 0; L < 3; ++L) {
        const short* WL_ = Wp + (size_t)(3 + L * 10) * 262144;
        const float* bL = (L == 0) ? bu1 : (L == 1) ? bu2 : bu3;
#pragma unroll 1
        for (int d = 0; d < NDOM; ++d) {
            int rlo = soff[d] - row0, rhi = soff[d + 1] - row0;
            rlo = rlo < 0 ? 0 : rlo;
            rhi = rhi > 64 ? 64 : rhi;
            if (rhi <= rlo) continue;
            const int nfm = (rlo < 32 ? 1 : 0) | (rhi > 32 ? 2 : 0);
            const short* pw = WL_ + (size_t)d * 262144 + w * 32768;
            if (nfm == 3)      pass512<3, true>(sH, sL, pw, lane, ah, al);
            else if (nfm == 1) pass512<1, true>(sH, sL, pw, lane, ah, al);
            else               pass512<2, true>(sH, sL, pw, lane, ah, al);
            __syncthreads();
            epi512<true, true, true>(sH, sL, ah, al, bL + d * HIDN, w, lane, rlo, rhi);
            __syncthreads();
        }
    }

    // ---- final 512->64: 4 waves, wave task (of, nf); coalesced float4 out ----
    if (w < 4) {
        const int of = w & 1, nff = w >> 1;
        const int rbase = nff * 32;
        const int r = rbase + (lane & 31);
#pragma unroll 1
        for (int d = 0; d < NDOM; ++d) {
            int rlo = soff[d] - row0, rhi = soff[d + 1] - row0;
            rlo = rlo < 0 ? 0 : rlo;
            rhi = rhi > 64 ? 64 : rhi;
            if (rhi <= rlo) continue;
            if (rhi <= rbase || rlo >= rbase + 32) continue;
            f32x16 fh, fl;
#pragma unroll
            for (int e = 0; e < 16; ++e) { fh[e] = 0.f; fl[e] = 0.f; }
            const short* pw = WoP + (size_t)d * 32768 + of * 16384 + lane * 8;
            bf16x8 wb[4];
#pragma unroll
            for (int dd = 0; dd < 4; ++dd) wb[dd] = *(const bf16x8*)(pw + dd * 512);
#pragma unroll
            for (int ks = 0; ks < 32; ++ks) {
                bf16x8 wk = wb[ks & 3];
                if (ks < 28) wb[ks & 3] = *(const bf16x8*)(pw + (ks + 4) * 512);
                const int base = (2 * ks + lh) * 512 + (lane & 31) * 8 + nff * 256;
                bf16x8 bhv = *(const bf16x8*)(sH + base);
                bf16x8 blv = *(const bf16x8*)(sL + base);
                fh = MFMA(wk, bhv, fh, 0, 0, 0);
                fl = MFMA(wk, blv, fl, 0, 0, 0);
            }
            if (r >= rlo && r < rhi) {
                const int orow = rowidx[row0 + r];
                float* op = out + (size_t)orow * STYLE + of * 32 + lh * 4;
                const float* bop = bo + d * STYLE + of * 32 + lh * 4;
#pragma unroll
                for (int q = 0; q < 4; ++q) {
                    float4 v;
                    v.x = fh[q * 4 + 0] + fl[q * 4 + 0] + bop[q * 8 + 0];
                    v.y = fh[q * 4 + 1] + fl[q * 4 + 1] + bop[q * 8 + 1];
                    v.z = fh[q * 4 + 2] + fl[q * 4 + 2] + bop[q * 8 + 2];
                    v.w = fh[q * 4 + 3] + fl[q * 4 + 3] + bop[q * 8 + 3];
                    *(float4*)(op + q * 8) = v;
                }
            }
        }
    }
}

// ---------------- launch ----------------

extern "C" void kernel_launch(void* const* d_in, const int* in_sizes, int n_in,
                              void* d_out, int out_size, void* d_ws, size_t ws_size,
                              hipStream_t stream) {
    const float* z   = (const float*)d_in[0];
    const int*   y   = (const int*)d_in[1];
    const float* W0  = (const float*)d_in[2];
    const float* b0  = (const float*)d_in[3];
    const float* W1  = (const float*)d_in[4];
    const float* b1  = (const float*)d_in[5];
    const float* W2  = (const float*)d_in[6];
    const float* b2  = (const float*)d_in[7];
    const float* W3  = (const float*)d_in[8];
    const float* b3  = (const float*)d_in[9];
    const float* Wu1 = (const float*)d_in[10];
    const float* bu1 = (const float*)d_in[11];
    const float* Wu2 = (const float*)d_in[12];
    const float* bu2 = (const float*)d_in[13];
    const float* Wu3 = (const float*)d_in[14];
    const float* bu3 = (const float*)d_in[15];
    const float* Wo  = (const float*)d_in[16];
    const float* bo  = (const float*)d_in[17];
    float* out = (float*)d_out;

    short* Wp   = (short*)d_ws;                      // 33 * 262144 shorts (16.5 MB)
    short* W0p  = Wp + (size_t)33 * 262144;          // 8192 shorts
    short* WoP  = W0p + 8192;                        // 10 * 32768 shorts
    int* rowidx  = (int*)(WoP + (size_t)10 * 32768); // NB ints
    int* counts  = rowidx + NB;                      // NDOM
    int* cursors = counts + NDOM;                    // NDOM

    hipMemsetAsync(counts, 0, sizeof(int) * 2 * NDOM, stream);
    k_hist<<<NB / 256, 256, 0, stream>>>(y, counts);
    k_scatter<<<NB / 256, 256, 0, stream>>>(y, counts, cursors, rowidx);
    k_prep<<<539, 256, 0, stream>>>(W1, W2, W3, Wu1, Wu2, Wu3, W0, Wo, Wp, W0p, WoP);
    k_fused<<<NWIN, 512, 0, stream>>>(z, rowidx, counts, Wp, W0p, WoP,
                                      b0, b1, b2, b3, bu1, bu2, bu3, bo, out);
}

// Round 7
// 258.203 us; speedup vs baseline: 1.0056x; 1.0056x over previous
//
#include <hip/hip_runtime.h>

#define NB 16384
#define NDOM 10
#define HIDN 512
#define STYLE 64
#define NWIN 256   // NB / 64

typedef short bf16x8 __attribute__((ext_vector_type(8)));
typedef float f32x16 __attribute__((ext_vector_type(16)));

#define MFMA __builtin_amdgcn_mfma_f32_32x32x16_bf16

// ---------------- bf16 helpers ----------------

__device__ __forceinline__ unsigned bfr_hi(float x) {
    unsigned u = __float_as_uint(x);
    return (u + 0x7fffu + ((u >> 16) & 1u)) & 0xffff0000u;  // RNE bf16 in high bits
}

__device__ __forceinline__ unsigned cvtpk(float a, float b) {
    unsigned r;
    asm("v_cvt_pk_bf16_f32 %0, %1, %2" : "=v"(r) : "v"(a), "v"(b));
    return r;   // [15:0]=bf16(a), [31:16]=bf16(b)
}

__device__ __forceinline__ void cvhalf2(const float4& x, const float4& y, uint4& h, uint4& l) {
    float xs[8] = {x.x, x.y, x.z, x.w, y.x, y.y, y.z, y.w};
    unsigned hh[8], ll[8];
#pragma unroll
    for (int i = 0; i < 8; ++i) {
        unsigned hb = bfr_hi(xs[i]);
        hh[i] = hb;
        ll[i] = bfr_hi(xs[i] - __uint_as_float(hb));
    }
    h = make_uint4((hh[0] >> 16) | (hh[1] & 0xffff0000u), (hh[2] >> 16) | (hh[3] & 0xffff0000u),
                   (hh[4] >> 16) | (hh[5] & 0xffff0000u), (hh[6] >> 16) | (hh[7] & 0xffff0000u));
    l = make_uint4((ll[0] >> 16) | (ll[1] & 0xffff0000u), (ll[2] >> 16) | (ll[3] & 0xffff0000u),
                   (ll[4] >> 16) | (ll[5] & 0xffff0000u), (ll[6] >> 16) | (ll[7] & 0xffff0000u));
}

// ---------------- bucketing ----------------

__global__ void k_hist(const int* __restrict__ y, int* __restrict__ counts) {
    int b = blockIdx.x * 256 + threadIdx.x;
    int d = y[b];
    int lane = threadIdx.x & 63;
#pragma unroll
    for (int dd = 0; dd < NDOM; ++dd) {
        unsigned long long bal = __ballot(d == dd);
        if (bal != 0ULL && d == dd && lane == __builtin_ctzll(bal))
            atomicAdd(&counts[dd], (int)__popcll(bal));
    }
}

__global__ void k_scatter(const int* __restrict__ y, const int* __restrict__ counts,
                          int* __restrict__ cursors, int* __restrict__ rowidx) {
    __shared__ int soff[NDOM];
    if (threadIdx.x == 0) {
        int s = 0;
        for (int dd = 0; dd < NDOM; ++dd) { soff[dd] = s; s += counts[dd]; }
    }
    __syncthreads();
    int b = blockIdx.x * 256 + threadIdx.x;
    int d = y[b];
    int lane = threadIdx.x & 63;
#pragma unroll
    for (int dd = 0; dd < NDOM; ++dd) {
        unsigned long long bal = __ballot(d == dd);
        if (bal == 0ULL) continue;
        int leader = __builtin_ctzll(bal);
        int base = 0;
        if (d == dd && lane == leader)
            base = atomicAdd(&cursors[dd], (int)__popcll(bal));
        base = __shfl(base, leader);
        if (d == dd) {
            int rank = (int)__popcll(bal & ((1ULL << lane) - 1ULL));
            rowidx[soff[dd] + base + rank] = b;
        }
    }
}

// ---------------- weight prep (single bf16, frag-linear) -------------------
// Big mats (512x512): per (mat, w) block of 32768 shorts:
//   addr = ks*1024 + of*512 + k8*256 + c5*8 + j ; k = ks*16+k8*8+j, col = w*64+of*32+c5
// mats: 0..2 = W1..W3 ; 3+d = Wu1[d] ; 13+d = Wu2[d] ; 23+d = Wu3[d]
// W0 (16x512): granule g: w=g>>7, of=(g>>6)&1, k8=(g>>5)&1, c5=g&31 at W0p+g*8
// Wo (per dom 512x64): granule g: w1=g>>11, ks=(g>>6)&31, k8=(g>>5)&1, c5=g&31

__global__ void k_prep(const float* __restrict__ W1, const float* __restrict__ W2,
                       const float* __restrict__ W3, const float* __restrict__ Wu1,
                       const float* __restrict__ Wu2, const float* __restrict__ Wu3,
                       const float* __restrict__ W0, const float* __restrict__ Wo,
                       short* __restrict__ Wp, short* __restrict__ W0p,
                       short* __restrict__ WoP)
{
    const int b = blockIdx.x;
    const int t = threadIdx.x;
    if (b < 528) {
        __shared__ float Ld[64][66];
        const int mat = b >> 4, w = (b >> 1) & 7, sh = b & 1;
        const float* src;
        if (mat < 3) src = (mat == 0 ? W1 : (mat == 1 ? W2 : W3));
        else {
            int g = (mat - 3) / 10, d = (mat - 3) % 10;
            src = (g == 0 ? Wu1 : (g == 1 ? Wu2 : Wu3)) + (size_t)d * HIDN * HIDN;
        }
        short* dst = Wp + (size_t)mat * 262144 + w * 32768;
        for (int s = sh * 4; s < sh * 4 + 4; ++s) {
            __syncthreads();
            const int r4 = t >> 6, c = t & 63;
#pragma unroll
            for (int p = 0; p < 16; ++p) {
                int k = s * 64 + p * 4 + r4;
                Ld[p * 4 + r4][c] = src[(size_t)k * HIDN + w * 64 + c];
            }
            __syncthreads();
#pragma unroll
            for (int i = 0; i < 2; ++i) {
                int g = i * 256 + t;
                int ksl = g >> 7, of = (g >> 6) & 1, k8 = (g >> 5) & 1, c5 = g & 31;
                int kk = ksl * 16 + k8 * 8;
                unsigned pk[4];
#pragma unroll
                for (int j2 = 0; j2 < 4; ++j2) {
                    unsigned h0 = bfr_hi(Ld[kk + 2 * j2][of * 32 + c5]);
                    unsigned h1 = bfr_hi(Ld[kk + 2 * j2 + 1][of * 32 + c5]);
                    pk[j2] = (h0 >> 16) | (h1 & 0xffff0000u);
                }
                int ksg = s * 4 + ksl;
                *(uint4*)(dst + ksg * 1024 + of * 512 + k8 * 256 + c5 * 8) =
                    make_uint4(pk[0], pk[1], pk[2], pk[3]);
            }
        }
    } else if (b == 528) {
#pragma unroll
        for (int i = 0; i < 4; ++i) {
            int g = i * 256 + t;   // 1024 granules
            int w = g >> 7, of = (g >> 6) & 1, k8 = (g >> 5) & 1, c5 = g & 31;
            int col = w * 64 + of * 32 + c5;
            unsigned pk[4];
#pragma unroll
            for (int j2 = 0; j2 < 4; ++j2) {
                unsigned h0 = bfr_hi(W0[(size_t)(k8 * 8 + 2 * j2) * HIDN + col]);
                unsigned h1 = bfr_hi(W0[(size_t)(k8 * 8 + 2 * j2 + 1) * HIDN + col]);
                pk[j2] = (h0 >> 16) | (h1 & 0xffff0000u);
            }
            *(uint4*)(W0p + g * 8) = make_uint4(pk[0], pk[1], pk[2], pk[3]);
        }
    } else {
        const int dom = b - 529;
        const float* src = Wo + (size_t)dom * HIDN * STYLE;
        short* dst = WoP + (size_t)dom * 32768;
#pragma unroll
        for (int i = 0; i < 16; ++i) {
            int g = i * 256 + t;   // 4096 granules
            int w1 = g >> 11, ks = (g >> 6) & 31, k8 = (g >> 5) & 1, c5 = g & 31;
            int col = w1 * 32 + c5;
            int k0 = ks * 16 + k8 * 8;
            unsigned pk[4];
#pragma unroll
            for (int j2 = 0; j2 < 4; ++j2) {
                unsigned h0 = bfr_hi(src[(size_t)(k0 + 2 * j2) * STYLE + col]);
                unsigned h1 = bfr_hi(src[(size_t)(k0 + 2 * j2 + 1) * STYLE + col]);
                pk[j2] = (h0 >> 16) | (h1 & 0xffff0000u);
            }
            *(uint4*)(dst + g * 8) = make_uint4(pk[0], pk[1], pk[2], pk[3]);
        }
    }
}

// ---------------- fused persistent kernel ----------------
// 256 blocks x 512 threads (8 waves), block = 64 sorted rows.
// LDS caps residency at 1 block/CU (128.5 KiB) -> launch_bounds(512,1):
// 256-VGPR budget, no spills (round-6 regression was launch_bounds(512,2)'s
// 128-VGPR cap spilling the pipeline state to scratch inside the K-loop).
// h in LDS: octet o=k>>3, line idx = o*512 + row*8 (shorts), 16B/line.
// Operand-swapped MFMA: A = weights (m=outcol), B = activations (n=batchrow).
// Wave w owns outcols [64w,64w+64) (of=2); nf=2 batchrow groups of 32.
// Weight prefetch ring depth 4; h-frags software-pipelined 1 ks ahead.

template<int NFM, bool BLO>
__device__ __forceinline__ void pass512(const short* __restrict__ sH,
                                        const short* __restrict__ sL,
                                        const short* __restrict__ pW, int lane,
                                        f32x16 ah[2][2], f32x16 al[2][2])
{
#pragma unroll
    for (int of = 0; of < 2; ++of)
#pragma unroll
        for (int nf = 0; nf < 2; ++nf)
            if (NFM & (1 << nf)) {
#pragma unroll
                for (int e = 0; e < 16; ++e) ah[of][nf][e] = 0.f;
                if (BLO)
#pragma unroll
                    for (int e = 0; e < 16; ++e) al[of][nf][e] = 0.f;
            }
    const short* pWl = pW + lane * 8;
    const int rb = (lane & 31) * 8;
    const int lh = lane >> 5;
    // weight ring, depth 4 (8 dwordx4 loads in flight)
    bf16x8 wv[4][2];
#pragma unroll
    for (int d = 0; d < 4; ++d) {
        wv[d][0] = *(const bf16x8*)(pWl + d * 1024);
        wv[d][1] = *(const bf16x8*)(pWl + d * 1024 + 512);
    }
    // h-frag double buffer (read 1 ks ahead)
    bf16x8 hb[2][2], lb[2][2];
    const int base0 = lh * 512 + rb;
#pragma unroll
    for (int nf = 0; nf < 2; ++nf)
        if (NFM & (1 << nf)) {
            hb[0][nf] = *(const bf16x8*)(sH + base0 + nf * 256);
            if (BLO) lb[0][nf] = *(const bf16x8*)(sL + base0 + nf * 256);
        }
#pragma unroll
    for (int ks = 0; ks < 32; ++ks) {
        const int pc = ks & 1, pn = pc ^ 1;
        bf16x8 w0 = wv[ks & 3][0], w1 = wv[ks & 3][1];
        if (ks < 28) {
            wv[ks & 3][0] = *(const bf16x8*)(pWl + (ks + 4) * 1024);
            wv[ks & 3][1] = *(const bf16x8*)(pWl + (ks + 4) * 1024 + 512);
        }
        if (ks < 31) {
            const int basen = (2 * (ks + 1) + lh) * 512 + rb;
#pragma unroll
            for (int nf = 0; nf < 2; ++nf)
                if (NFM & (1 << nf)) {
                    hb[pn][nf] = *(const bf16x8*)(sH + basen + nf * 256);
                    if (BLO) lb[pn][nf] = *(const bf16x8*)(sL + basen + nf * 256);
                }
        }
#pragma unroll
        for (int nf = 0; nf < 2; ++nf) {
            if (!(NFM & (1 << nf))) continue;
            ah[0][nf] = MFMA(w0, hb[pc][nf], ah[0][nf], 0, 0, 0);
            ah[1][nf] = MFMA(w1, hb[pc][nf], ah[1][nf], 0, 0, 0);
            if (BLO) {
                al[0][nf] = MFMA(w0, lb[pc][nf], al[0][nf], 0, 0, 0);
                al[1][nf] = MFMA(w1, lb[pc][nf], al[1][nf], 0, 0, 0);
            }
        }
    }
}

// epilogue: merge accs + bias (+ReLU), pack bf16 hi(/lo), shuffle-repack so each
// half-wave writes full contiguous 16B lines (conflict-free ds_write_b128).
template<bool BLO, bool WLO, bool RELU>
__device__ __forceinline__ void epi512(short* __restrict__ sH, short* __restrict__ sL,
                                       f32x16 ah[2][2], f32x16 al[2][2],
                                       const float* __restrict__ bias,
                                       int w, int lane, int rlo, int rhi)
{
    const int lh = lane >> 5;
#pragma unroll
    for (int nf = 0; nf < 2; ++nf) {
        const int row = nf * 32 + (lane & 31);
        const bool pred = (row >= rlo && row < rhi);
#pragma unroll
        for (int of = 0; of < 2; ++of) {
            unsigned mh[4][2], ml[4][2];
#pragma unroll
            for (int q = 0; q < 4; ++q) {
                // my 4 k-values: k = of*32 + q*8 + lh*4 + j
                float v[4];
#pragma unroll
                for (int j = 0; j < 4; ++j) {
                    float x = ah[of][nf][q * 4 + j];
                    if (BLO) x += al[of][nf][q * 4 + j];
                    x += bias[w * 64 + of * 32 + q * 8 + lh * 4 + j];
                    if (RELU) x = fmaxf(x, 0.f);
                    v[j] = x;
                }
                mh[q][0] = cvtpk(v[0], v[1]);
                mh[q][1] = cvtpk(v[2], v[3]);
                if (WLO) {
                    float l0 = v[0] - __uint_as_float(mh[q][0] << 16);
                    float l1 = v[1] - __uint_as_float(mh[q][0] & 0xffff0000u);
                    float l2 = v[2] - __uint_as_float(mh[q][1] << 16);
                    float l3 = v[3] - __uint_as_float(mh[q][1] & 0xffff0000u);
                    ml[q][0] = cvtpk(l0, l1);
                    ml[q][1] = cvtpk(l2, l3);
                }
            }
            // exchange with lane^32 (same row, other half of each 16B line);
            // lane writes full lines for q = 2t + lh  -> contiguous per half-wave
#pragma unroll
            for (int t = 0; t < 2; ++t) {
                const int q = 2 * t + lh;
                const int qs = 2 * t + (lh ^ 1);
                unsigned r0 = (unsigned)__shfl_xor((int)mh[qs][0], 32);
                unsigned r1 = (unsigned)__shfl_xor((int)mh[qs][1], 32);
                uint4 line = lh == 0 ? make_uint4(mh[q][0], mh[q][1], r0, r1)
                                     : make_uint4(r0, r1, mh[q][0], mh[q][1]);
                const int o = w * 8 + of * 4 + q;
                if (pred) *(uint4*)(sH + o * 512 + row * 8) = line;
                if (WLO) {
                    unsigned s0 = (unsigned)__shfl_xor((int)ml[qs][0], 32);
                    unsigned s1 = (unsigned)__shfl_xor((int)ml[qs][1], 32);
                    uint4 lin2 = lh == 0 ? make_uint4(ml[q][0], ml[q][1], s0, s1)
                                         : make_uint4(s0, s1, ml[q][0], ml[q][1]);
                    if (pred) *(uint4*)(sL + o * 512 + row * 8) = lin2;
                }
            }
        }
    }
}

__global__ __launch_bounds__(512, 1)
void k_fused(const float* __restrict__ z, const int* __restrict__ rowidx,
             const int* __restrict__ counts,
             const short* __restrict__ Wp, const short* __restrict__ W0p,
             const short* __restrict__ WoP,
             const float* __restrict__ b0, const float* __restrict__ b1,
             const float* __restrict__ b2, const float* __restrict__ b3,
             const float* __restrict__ bu1, const float* __restrict__ bu2,
             const float* __restrict__ bu3, const float* __restrict__ bo,
             float* __restrict__ out)
{
    __shared__ short sH[32768];   // 64 KiB  (h hi)
    __shared__ short sL[32768];   // 64 KiB  (h lo; valid from layer-3 output on)
    __shared__ int soff[NDOM + 1];

    // XCD-chunked bijective swizzle: neighbors share a domain -> L2 reuse
    const int win = (blockIdx.x & 7) * 32 + (blockIdx.x >> 3);
    const int row0 = win * 64;
    const int tid = threadIdx.x;
    const int lane = tid & 63;
    const int w = tid >> 6;
    const int lh = lane >> 5;

    if (tid == 0) {
        int s = 0;
#pragma unroll
        for (int dd = 0; dd < NDOM; ++dd) { soff[dd] = s; s += counts[dd]; }
        soff[NDOM] = s;
    }

    f32x16 ah[2][2], al[2][2];

    // ---- layer 0: z (K=16) -> h (hi-only out; z itself split hi/lo) ----
    {
#pragma unroll
        for (int a = 0; a < 2; ++a)
#pragma unroll
            for (int b = 0; b < 2; ++b)
#pragma unroll
                for (int e = 0; e < 16; ++e) { ah[a][b][e] = 0.f; al[a][b][e] = 0.f; }
        const short* pw0 = W0p + w * 1024 + lane * 8;
        bf16x8 w0 = *(const bf16x8*)(pw0);
        bf16x8 w1 = *(const bf16x8*)(pw0 + 512);
#pragma unroll
        for (int nf = 0; nf < 2; ++nf) {
            int r = nf * 32 + (lane & 31);
            int src = rowidx[row0 + r];
            const float* zp = z + (size_t)src * 16 + lh * 8;
            float4 f0 = *(const float4*)zp;
            float4 f1 = *(const float4*)(zp + 4);
            uint4 h, l;
            cvhalf2(f0, f1, h, l);
            bf16x8 zh = *(bf16x8*)&h;
            bf16x8 zl = *(bf16x8*)&l;
            ah[0][nf] = MFMA(w0, zh, ah[0][nf], 0, 0, 0);
            ah[1][nf] = MFMA(w1, zh, ah[1][nf], 0, 0, 0);
            al[0][nf] = MFMA(w0, zl, al[0][nf], 0, 0, 0);
            al[1][nf] = MFMA(w1, zl, al[1][nf], 0, 0, 0);
        }
        // fold z-lo contribution into hi acc, then write hi-only
#pragma unroll
        for (int a = 0; a < 2; ++a)
#pragma unroll
            for (int b = 0; b < 2; ++b)
#pragma unroll
                for (int e = 0; e < 16; ++e) ah[a][b][e] += al[a][b][e];
        epi512<false, false, true>(sH, sL, ah, al, b0, w, lane, 0, 64);
        __syncthreads();
    }

    // ---- trunk layers 1-3 (h hi-only inputs; layer 3 writes hi+lo) ----
#pragma unroll 1
    for (int m = 0; m < 3; ++m) {
        const float* bp = (m == 0) ? b1 : (m == 1) ? b2 : b3;
        pass512<3, false>(sH, sL, Wp + (size_t)m * 262144 + w * 32768, lane, ah, al);
        __syncthreads();
        if (m < 2) epi512<false, false, true>(sH, sL, ah, al, bp, w, lane, 0, 64);
        else       epi512<false, true,  true>(sH, sL, ah, al, bp, w, lane, 0, 64);
        __syncthreads();
    }

    // ---- head layers: per-domain, nf-granular (32-row groups) ----
#pragma unroll 1
    for (int L = 0; L < 3; ++L) {
        const short* WL_ = Wp + (size_t)(3 + L * 10) * 262144;
        const float* bL = (L == 0) ? bu1 : (L == 1) ? bu2 : bu3;
#pragma unroll 1
        for (int d = 0; d < NDOM; ++d) {
            int rlo = soff[d] - row0, rhi = soff[d + 1] - row0;
            rlo = rlo < 0 ? 0 : rlo;
            rhi = rhi > 64 ? 64 : rhi;
            if (rhi <= rlo) continue;
            const int nfm = (rlo < 32 ? 1 : 0) | (rhi > 32 ? 2 : 0);
            const short* pw = WL_ + (size_t)d * 262144 + w * 32768;
            if (nfm == 3)      pass512<3, true>(sH, sL, pw, lane, ah, al);
            else if (nfm == 1) pass512<1, true>(sH, sL, pw, lane, ah, al);
            else               pass512<2, true>(sH, sL, pw, lane, ah, al);
            __syncthreads();
            epi512<true, true, true>(sH, sL, ah, al, bL + d * HIDN, w, lane, rlo, rhi);
            __syncthreads();
        }
    }

    // ---- final 512->64: 4 waves, wave task (of, nf); coalesced float4 out ----
    if (w < 4) {
        const int of = w & 1, nff = w >> 1;
        const int rbase = nff * 32;
        const int r = rbase + (lane & 31);
#pragma unroll 1
        for (int d = 0; d < NDOM; ++d) {
            int rlo = soff[d] - row0, rhi = soff[d + 1] - row0;
            rlo = rlo < 0 ? 0 : rlo;
            rhi = rhi > 64 ? 64 : rhi;
            if (rhi <= rlo) continue;
            if (rhi <= rbase || rlo >= rbase + 32) continue;
            f32x16 fh, fl;
#pragma unroll
            for (int e = 0; e < 16; ++e) { fh[e] = 0.f; fl[e] = 0.f; }
            const short* pw = WoP + (size_t)d * 32768 + of * 16384 + lane * 8;
            bf16x8 wb[4];
#pragma unroll
            for (int dd = 0; dd < 4; ++dd) wb[dd] = *(const bf16x8*)(pw + dd * 512);
#pragma unroll
            for (int ks = 0; ks < 32; ++ks) {
                bf16x8 wk = wb[ks & 3];
                if (ks < 28) wb[ks & 3] = *(const bf16x8*)(pw + (ks + 4) * 512);
                const int base = (2 * ks + lh) * 512 + (lane & 31) * 8 + nff * 256;
                bf16x8 bhv = *(const bf16x8*)(sH + base);
                bf16x8 blv = *(const bf16x8*)(sL + base);
                fh = MFMA(wk, bhv, fh, 0, 0, 0);
                fl = MFMA(wk, blv, fl, 0, 0, 0);
            }
            if (r >= rlo && r < rhi) {
                const int orow = rowidx[row0 + r];
                float* op = out + (size_t)orow * STYLE + of * 32 + lh * 4;
                const float* bop = bo + d * STYLE + of * 32 + lh * 4;
#pragma unroll
                for (int q = 0; q < 4; ++q) {
                    float4 v;
                    v.x = fh[q * 4 + 0] + fl[q * 4 + 0] + bop[q * 8 + 0];
                    v.y = fh[q * 4 + 1] + fl[q * 4 + 1] + bop[q * 8 + 1];
                    v.z = fh[q * 4 + 2] + fl[q * 4 + 2] + bop[q * 8 + 2];
                    v.w = fh[q * 4 + 3] + fl[q * 4 + 3] + bop[q * 8 + 3];
                    *(float4*)(op + q * 8) = v;
                }
            }
        }
    }
}

// ---------------- launch ----------------

extern "C" void kernel_launch(void* const* d_in, const int* in_sizes, int n_in,
                              void* d_out, int out_size, void* d_ws, size_t ws_size,
                              hipStream_t stream) {
    const float* z   = (const float*)d_in[0];
    const int*   y   = (const int*)d_in[1];
    const float* W0  = (const float*)d_in[2];
    const float* b0  = (const float*)d_in[3];
    const float* W1  = (const float*)d_in[4];
    const float* b1  = (const float*)d_in[5];
    const float* W2  = (const float*)d_in[6];
    const float* b2  = (const float*)d_in[7];
    const float* W3  = (const float*)d_in[8];
    const float* b3  = (const float*)d_in[9];
    const float* Wu1 = (const float*)d_in[10];
    const float* bu1 = (const float*)d_in[11];
    const float* Wu2 = (const float*)d_in[12];
    const float* bu2 = (const float*)d_in[13];
    const float* Wu3 = (const float*)d_in[14];
    const float* bu3 = (const float*)d_in[15];
    const float* Wo  = (const float*)d_in[16];
    const float* bo  = (const float*)d_in[17];
    float* out = (float*)d_out;

    short* Wp   = (short*)d_ws;                      // 33 * 262144 shorts (16.5 MB)
    short* W0p  = Wp + (size_t)33 * 262144;          // 8192 shorts
    short* WoP  = W0p + 8192;                        // 10 * 32768 shorts
    int* rowidx  = (int*)(WoP + (size_t)10 * 32768); // NB ints
    int* counts  = rowidx + NB;                      // NDOM
    int* cursors = counts + NDOM;                    // NDOM

    hipMemsetAsync(counts, 0, sizeof(int) * 2 * NDOM, stream);
    k_hist<<<NB / 256, 256, 0, stream>>>(y, counts);
    k_scatter<<<NB / 256, 256, 0, stream>>>(y, counts, cursors, rowidx);
    k_prep<<<539, 256, 0, stream>>>(W1, W2, W3, Wu1, Wu2, Wu3, W0, Wo, Wp, W0p, WoP);
    k_fused<<<NWIN, 512, 0, stream>>>(z, rowidx, counts, Wp, W0p, WoP,
                                      b0, b1, b2, b3, bu1, bu2, bu3, bo, out);
}

// Round 8
// 210.251 us; speedup vs baseline: 1.2349x; 1.2281x over previous
//
#include <hip/hip_runtime.h>

#define NB 16384
#define NDOM 10
#define HIDN 512
#define STYLE 64
#define NWIN 256   // NB / 64

typedef short bf16x8 __attribute__((ext_vector_type(8)));
typedef float f32x16 __attribute__((ext_vector_type(16)));

#define MFMA __builtin_amdgcn_mfma_f32_32x32x16_bf16

// ---------------- bf16 helpers ----------------

__device__ __forceinline__ unsigned bfr_hi(float x) {
    unsigned u = __float_as_uint(x);
    return (u + 0x7fffu + ((u >> 16) & 1u)) & 0xffff0000u;  // RNE bf16 in high bits
}

__device__ __forceinline__ unsigned cvtpk(float a, float b) {
    unsigned r;
    asm("v_cvt_pk_bf16_f32 %0, %1, %2" : "=v"(r) : "v"(a), "v"(b));
    return r;   // [15:0]=bf16(a), [31:16]=bf16(b)
}

__device__ __forceinline__ void cvhalf2(const float4& x, const float4& y, uint4& h, uint4& l) {
    float xs[8] = {x.x, x.y, x.z, x.w, y.x, y.y, y.z, y.w};
    unsigned hh[8], ll[8];
#pragma unroll
    for (int i = 0; i < 8; ++i) {
        unsigned hb = bfr_hi(xs[i]);
        hh[i] = hb;
        ll[i] = bfr_hi(xs[i] - __uint_as_float(hb));
    }
    h = make_uint4((hh[0] >> 16) | (hh[1] & 0xffff0000u), (hh[2] >> 16) | (hh[3] & 0xffff0000u),
                   (hh[4] >> 16) | (hh[5] & 0xffff0000u), (hh[6] >> 16) | (hh[7] & 0xffff0000u));
    l = make_uint4((ll[0] >> 16) | (ll[1] & 0xffff0000u), (ll[2] >> 16) | (ll[3] & 0xffff0000u),
                   (ll[4] >> 16) | (ll[5] & 0xffff0000u), (ll[6] >> 16) | (ll[7] & 0xffff0000u));
}

// ---------------- bucketing: hist + scan + scatter in ONE block ------------

__global__ __launch_bounds__(1024)
void k_sort(const int* __restrict__ y, int* __restrict__ offsets,
            int* __restrict__ rowidx)
{
    __shared__ int hist[NDOM], cur[NDOM];
    const int t = threadIdx.x, lane = t & 63;
    if (t < NDOM) hist[t] = 0;
    __syncthreads();
    for (int i = t; i < NB; i += 1024) {
        int d = y[i];
#pragma unroll
        for (int dd = 0; dd < NDOM; ++dd) {
            unsigned long long bal = __ballot(d == dd);
            if (bal != 0ULL && d == dd && lane == __builtin_ctzll(bal))
                atomicAdd(&hist[dd], (int)__popcll(bal));
        }
    }
    __syncthreads();
    if (t == 0) {
        int s = 0;
        for (int dd = 0; dd < NDOM; ++dd) { offsets[dd] = s; cur[dd] = s; s += hist[dd]; }
        offsets[NDOM] = s;
    }
    __syncthreads();
    for (int i = t; i < NB; i += 1024) {
        int d = y[i];
#pragma unroll
        for (int dd = 0; dd < NDOM; ++dd) {
            unsigned long long bal = __ballot(d == dd);
            if (bal == 0ULL) continue;
            int leader = __builtin_ctzll(bal);
            int base = 0;
            if (d == dd && lane == leader)
                base = atomicAdd(&cur[dd], (int)__popcll(bal));
            base = __shfl(base, leader);
            if (d == dd) {
                int rank = (int)__popcll(bal & ((1ULL << lane) - 1ULL));
                rowidx[base + rank] = i;
            }
        }
    }
}

// ---------------- weight prep (single bf16, frag-linear) -------------------
// Big mats (512x512): per (mat, w) block of 32768 shorts:
//   addr = ks*1024 + of*512 + k8*256 + c5*8 + j ; k = ks*16+k8*8+j, col = w*64+of*32+c5
// mats: 0..2 = W1..W3 ; 3+d = Wu1[d] ; 13+d = Wu2[d] ; 23+d = Wu3[d]
// W0 (16x512): granule g: w=g>>7, of=(g>>6)&1, k8=(g>>5)&1, c5=g&31 at W0p+g*8
// Wo (per dom 512x64): granule g: w1=g>>11, ks=(g>>6)&31, k8=(g>>5)&1, c5=g&31

__global__ void k_prep(const float* __restrict__ W1, const float* __restrict__ W2,
                       const float* __restrict__ W3, const float* __restrict__ Wu1,
                       const float* __restrict__ Wu2, const float* __restrict__ Wu3,
                       const float* __restrict__ W0, const float* __restrict__ Wo,
                       short* __restrict__ Wp, short* __restrict__ W0p,
                       short* __restrict__ WoP)
{
    const int b = blockIdx.x;
    const int t = threadIdx.x;
    if (b < 528) {
        __shared__ float Ld[64][66];
        const int mat = b >> 4, w = (b >> 1) & 7, sh = b & 1;
        const float* src;
        if (mat < 3) src = (mat == 0 ? W1 : (mat == 1 ? W2 : W3));
        else {
            int g = (mat - 3) / 10, d = (mat - 3) % 10;
            src = (g == 0 ? Wu1 : (g == 1 ? Wu2 : Wu3)) + (size_t)d * HIDN * HIDN;
        }
        short* dst = Wp + (size_t)mat * 262144 + w * 32768;
        for (int s = sh * 4; s < sh * 4 + 4; ++s) {
            __syncthreads();
            const int r4 = t >> 6, c = t & 63;
#pragma unroll
            for (int p = 0; p < 16; ++p) {
                int k = s * 64 + p * 4 + r4;
                Ld[p * 4 + r4][c] = src[(size_t)k * HIDN + w * 64 + c];
            }
            __syncthreads();
#pragma unroll
            for (int i = 0; i < 2; ++i) {
                int g = i * 256 + t;
                int ksl = g >> 7, of = (g >> 6) & 1, k8 = (g >> 5) & 1, c5 = g & 31;
                int kk = ksl * 16 + k8 * 8;
                unsigned pk[4];
#pragma unroll
                for (int j2 = 0; j2 < 4; ++j2) {
                    unsigned h0 = bfr_hi(Ld[kk + 2 * j2][of * 32 + c5]);
                    unsigned h1 = bfr_hi(Ld[kk + 2 * j2 + 1][of * 32 + c5]);
                    pk[j2] = (h0 >> 16) | (h1 & 0xffff0000u);
                }
                int ksg = s * 4 + ksl;
                *(uint4*)(dst + ksg * 1024 + of * 512 + k8 * 256 + c5 * 8) =
                    make_uint4(pk[0], pk[1], pk[2], pk[3]);
            }
        }
    } else if (b == 528) {
#pragma unroll
        for (int i = 0; i < 4; ++i) {
            int g = i * 256 + t;   // 1024 granules
            int w = g >> 7, of = (g >> 6) & 1, k8 = (g >> 5) & 1, c5 = g & 31;
            int col = w * 64 + of * 32 + c5;
            unsigned pk[4];
#pragma unroll
            for (int j2 = 0; j2 < 4; ++j2) {
                unsigned h0 = bfr_hi(W0[(size_t)(k8 * 8 + 2 * j2) * HIDN + col]);
                unsigned h1 = bfr_hi(W0[(size_t)(k8 * 8 + 2 * j2 + 1) * HIDN + col]);
                pk[j2] = (h0 >> 16) | (h1 & 0xffff0000u);
            }
            *(uint4*)(W0p + g * 8) = make_uint4(pk[0], pk[1], pk[2], pk[3]);
        }
    } else {
        const int dom = b - 529;
        const float* src = Wo + (size_t)dom * HIDN * STYLE;
        short* dst = WoP + (size_t)dom * 32768;
#pragma unroll
        for (int i = 0; i < 16; ++i) {
            int g = i * 256 + t;   // 4096 granules
            int w1 = g >> 11, ks = (g >> 6) & 31, k8 = (g >> 5) & 1, c5 = g & 31;
            int col = w1 * 32 + c5;
            int k0 = ks * 16 + k8 * 8;
            unsigned pk[4];
#pragma unroll
            for (int j2 = 0; j2 < 4; ++j2) {
                unsigned h0 = bfr_hi(src[(size_t)(k0 + 2 * j2) * STYLE + col]);
                unsigned h1 = bfr_hi(src[(size_t)(k0 + 2 * j2 + 1) * STYLE + col]);
                pk[j2] = (h0 >> 16) | (h1 & 0xffff0000u);
            }
            *(uint4*)(dst + g * 8) = make_uint4(pk[0], pk[1], pk[2], pk[3]);
        }
    }
}

// ---------------- fused persistent kernel ----------------
// 256 blocks x 512 threads (8 waves), block = 64 sorted rows.
// 512-thread wg => 2 waves/SIMD co-resident => HARD 256-reg/wave cap.
// Key: hi+lo activation contributions accumulate into ONE fp32 chain
// (64 AGPR accumulators), leaving headroom for the depth-4 weight ring
// + 1-ks-ahead LDS pipeline without scratch spills (round-6 regression).
// h in LDS: octet o=k>>3, line idx = o*512 + row*8 (shorts), 16B/line.
// Operand-swapped MFMA: A = weights (m=outcol), B = activations (n=batchrow).

template<int NFM, bool BLO>
__device__ __forceinline__ void pass512(const short* __restrict__ sH,
                                        const short* __restrict__ sL,
                                        const short* __restrict__ pW, int lane,
                                        f32x16 acc[2][2])
{
#pragma unroll
    for (int of = 0; of < 2; ++of)
#pragma unroll
        for (int nf = 0; nf < 2; ++nf)
            if (NFM & (1 << nf))
#pragma unroll
                for (int e = 0; e < 16; ++e) acc[of][nf][e] = 0.f;
    const short* pWl = pW + lane * 8;
    const int rb = (lane & 31) * 8;
    const int lh = lane >> 5;
    // weight ring, depth 4 (8 dwordx4 loads in flight)
    bf16x8 wv[4][2];
#pragma unroll
    for (int d = 0; d < 4; ++d) {
        wv[d][0] = *(const bf16x8*)(pWl + d * 1024);
        wv[d][1] = *(const bf16x8*)(pWl + d * 1024 + 512);
    }
    // h-frag double buffer (read 1 ks ahead)
    bf16x8 hb[2][2], lb[2][2];
    const int base0 = lh * 512 + rb;
#pragma unroll
    for (int nf = 0; nf < 2; ++nf)
        if (NFM & (1 << nf)) {
            hb[0][nf] = *(const bf16x8*)(sH + base0 + nf * 256);
            if (BLO) lb[0][nf] = *(const bf16x8*)(sL + base0 + nf * 256);
        }
#pragma unroll
    for (int ks = 0; ks < 32; ++ks) {
        const int pc = ks & 1, pn = pc ^ 1;
        bf16x8 w0 = wv[ks & 3][0], w1 = wv[ks & 3][1];
        if (ks < 28) {
            wv[ks & 3][0] = *(const bf16x8*)(pWl + (ks + 4) * 1024);
            wv[ks & 3][1] = *(const bf16x8*)(pWl + (ks + 4) * 1024 + 512);
        }
        if (ks < 31) {
            const int basen = (2 * (ks + 1) + lh) * 512 + rb;
#pragma unroll
            for (int nf = 0; nf < 2; ++nf)
                if (NFM & (1 << nf)) {
                    hb[pn][nf] = *(const bf16x8*)(sH + basen + nf * 256);
                    if (BLO) lb[pn][nf] = *(const bf16x8*)(sL + basen + nf * 256);
                }
        }
        // hi pass: 4 MFMAs, then lo pass: same chains, 32-cyc issue distance
#pragma unroll
        for (int nf = 0; nf < 2; ++nf) {
            if (!(NFM & (1 << nf))) continue;
            acc[0][nf] = MFMA(w0, hb[pc][nf], acc[0][nf], 0, 0, 0);
            acc[1][nf] = MFMA(w1, hb[pc][nf], acc[1][nf], 0, 0, 0);
        }
        if (BLO) {
#pragma unroll
            for (int nf = 0; nf < 2; ++nf) {
                if (!(NFM & (1 << nf))) continue;
                acc[0][nf] = MFMA(w0, lb[pc][nf], acc[0][nf], 0, 0, 0);
                acc[1][nf] = MFMA(w1, lb[pc][nf], acc[1][nf], 0, 0, 0);
            }
        }
    }
}

// epilogue: bias (+ReLU), pack bf16 hi(/lo), shuffle-repack so each half-wave
// writes full contiguous 16B lines (conflict-free ds_write_b128).
template<bool WLO, bool RELU>
__device__ __forceinline__ void epi512(short* __restrict__ sH, short* __restrict__ sL,
                                       f32x16 acc[2][2],
                                       const float* __restrict__ bias,
                                       int w, int lane, int rlo, int rhi)
{
    const int lh = lane >> 5;
#pragma unroll
    for (int nf = 0; nf < 2; ++nf) {
        const int row = nf * 32 + (lane & 31);
        const bool pred = (row >= rlo && row < rhi);
#pragma unroll
        for (int of = 0; of < 2; ++of) {
            unsigned mh[4][2], ml[4][2];
#pragma unroll
            for (int q = 0; q < 4; ++q) {
                // my 4 k-values: k = of*32 + q*8 + lh*4 + j
                float v[4];
#pragma unroll
                for (int j = 0; j < 4; ++j) {
                    float x = acc[of][nf][q * 4 + j];
                    x += bias[w * 64 + of * 32 + q * 8 + lh * 4 + j];
                    if (RELU) x = fmaxf(x, 0.f);
                    v[j] = x;
                }
                mh[q][0] = cvtpk(v[0], v[1]);
                mh[q][1] = cvtpk(v[2], v[3]);
                if (WLO) {
                    float l0 = v[0] - __uint_as_float(mh[q][0] << 16);
                    float l1 = v[1] - __uint_as_float(mh[q][0] & 0xffff0000u);
                    float l2 = v[2] - __uint_as_float(mh[q][1] << 16);
                    float l3 = v[3] - __uint_as_float(mh[q][1] & 0xffff0000u);
                    ml[q][0] = cvtpk(l0, l1);
                    ml[q][1] = cvtpk(l2, l3);
                }
            }
            // exchange with lane^32 (same row, other half of each 16B line);
            // lane writes full lines for q = 2t + lh -> contiguous per half-wave
#pragma unroll
            for (int t = 0; t < 2; ++t) {
                const int q = 2 * t + lh;
                const int qs = 2 * t + (lh ^ 1);
                unsigned r0 = (unsigned)__shfl_xor((int)mh[qs][0], 32);
                unsigned r1 = (unsigned)__shfl_xor((int)mh[qs][1], 32);
                uint4 line = lh == 0 ? make_uint4(mh[q][0], mh[q][1], r0, r1)
                                     : make_uint4(r0, r1, mh[q][0], mh[q][1]);
                const int o = w * 8 + of * 4 + q;
                if (pred) *(uint4*)(sH + o * 512 + row * 8) = line;
                if (WLO) {
                    unsigned s0 = (unsigned)__shfl_xor((int)ml[qs][0], 32);
                    unsigned s1 = (unsigned)__shfl_xor((int)ml[qs][1], 32);
                    uint4 lin2 = lh == 0 ? make_uint4(ml[q][0], ml[q][1], s0, s1)
                                         : make_uint4(s0, s1, ml[q][0], ml[q][1]);
                    if (pred) *(uint4*)(sL + o * 512 + row * 8) = lin2;
                }
            }
        }
    }
}

__global__ __launch_bounds__(512, 1)
void k_fused(const float* __restrict__ z, const int* __restrict__ rowidx,
             const int* __restrict__ offsets,
             const short* __restrict__ Wp, const short* __restrict__ W0p,
             const short* __restrict__ WoP,
             const float* __restrict__ b0, const float* __restrict__ b1,
             const float* __restrict__ b2, const float* __restrict__ b3,
             const float* __restrict__ bu1, const float* __restrict__ bu2,
             const float* __restrict__ bu3, const float* __restrict__ bo,
             float* __restrict__ out)
{
    __shared__ short sH[32768];   // 64 KiB  (h hi)
    __shared__ short sL[32768];   // 64 KiB  (h lo; valid from layer-3 output on)
    __shared__ int soff[NDOM + 1];

    // XCD-chunked bijective swizzle: neighbors share a domain -> L2 reuse
    const int win = (blockIdx.x & 7) * 32 + (blockIdx.x >> 3);
    const int row0 = win * 64;
    const int tid = threadIdx.x;
    const int lane = tid & 63;
    const int w = tid >> 6;
    const int lh = lane >> 5;

    if (tid < NDOM + 1) soff[tid] = offsets[tid];

    f32x16 acc[2][2];

    // ---- layer 0: z (K=16) -> h (hi-only out; z itself split hi/lo) ----
    {
#pragma unroll
        for (int a = 0; a < 2; ++a)
#pragma unroll
            for (int b = 0; b < 2; ++b)
#pragma unroll
                for (int e = 0; e < 16; ++e) acc[a][b][e] = 0.f;
        const short* pw0 = W0p + w * 1024 + lane * 8;
        bf16x8 w0 = *(const bf16x8*)(pw0);
        bf16x8 w1 = *(const bf16x8*)(pw0 + 512);
#pragma unroll
        for (int nf = 0; nf < 2; ++nf) {
            int r = nf * 32 + (lane & 31);
            int src = rowidx[row0 + r];
            const float* zp = z + (size_t)src * 16 + lh * 8;
            float4 f0 = *(const float4*)zp;
            float4 f1 = *(const float4*)(zp + 4);
            uint4 h, l;
            cvhalf2(f0, f1, h, l);
            bf16x8 zh = *(bf16x8*)&h;
            bf16x8 zl = *(bf16x8*)&l;
            acc[0][nf] = MFMA(w0, zh, acc[0][nf], 0, 0, 0);
            acc[1][nf] = MFMA(w1, zh, acc[1][nf], 0, 0, 0);
            acc[0][nf] = MFMA(w0, zl, acc[0][nf], 0, 0, 0);
            acc[1][nf] = MFMA(w1, zl, acc[1][nf], 0, 0, 0);
        }
        epi512<false, true>(sH, sL, acc, b0, w, lane, 0, 64);
        __syncthreads();
    }

    // ---- trunk layers 1-3 (h hi-only inputs; layer 3 writes hi+lo) ----
#pragma unroll 1
    for (int m = 0; m < 3; ++m) {
        const float* bp = (m == 0) ? b1 : (m == 1) ? b2 : b3;
        pass512<3, false>(sH, sL, Wp + (size_t)m * 262144 + w * 32768, lane, acc);
        __syncthreads();
        if (m < 2) epi512<false, true>(sH, sL, acc, bp, w, lane, 0, 64);
        else       epi512<true,  true>(sH, sL, acc, bp, w, lane, 0, 64);
        __syncthreads();
    }

    // ---- head layers: per-domain, nf-granular (32-row groups) ----
#pragma unroll 1
    for (int L = 0; L < 3; ++L) {
        const short* WL_ = Wp + (size_t)(3 + L * 10) * 262144;
        const float* bL = (L == 0) ? bu1 : (L == 1) ? bu2 : bu3;
#pragma unroll 1
        for (int d = 0; d < NDOM; ++d) {
            int rlo = soff[d] - row0, rhi = soff[d + 1] - row0;
            rlo = rlo < 0 ? 0 : rlo;
            rhi = rhi > 64 ? 64 : rhi;
            if (rhi <= rlo) continue;
            const int nfm = (rlo < 32 ? 1 : 0) | (rhi > 32 ? 2 : 0);
            const short* pw = WL_ + (size_t)d * 262144 + w * 32768;
            if (nfm == 3)      pass512<3, true>(sH, sL, pw, lane, acc);
            else if (nfm == 1) pass512<1, true>(sH, sL, pw, lane, acc);
            else               pass512<2, true>(sH, sL, pw, lane, acc);
            __syncthreads();
            epi512<true, true>(sH, sL, acc, bL + d * HIDN, w, lane, rlo, rhi);
            __syncthreads();
        }
    }

    // ---- final 512->64: 4 waves, wave task (of, nf); coalesced float4 out ----
    if (w < 4) {
        const int of = w & 1, nff = w >> 1;
        const int rbase = nff * 32;
        const int r = rbase + (lane & 31);
#pragma unroll 1
        for (int d = 0; d < NDOM; ++d) {
            int rlo = soff[d] - row0, rhi = soff[d + 1] - row0;
            rlo = rlo < 0 ? 0 : rlo;
            rhi = rhi > 64 ? 64 : rhi;
            if (rhi <= rlo) continue;
            if (rhi <= rbase || rlo >= rbase + 32) continue;
            f32x16 fh, fl;   // split chains here: only 1 chain/wave otherwise
#pragma unroll
            for (int e = 0; e < 16; ++e) { fh[e] = 0.f; fl[e] = 0.f; }
            const short* pw = WoP + (size_t)d * 32768 + of * 16384 + lane * 8;
            bf16x8 wb[4];
#pragma unroll
            for (int dd = 0; dd < 4; ++dd) wb[dd] = *(const bf16x8*)(pw + dd * 512);
#pragma unroll
            for (int ks = 0; ks < 32; ++ks) {
                bf16x8 wk = wb[ks & 3];
                if (ks < 28) wb[ks & 3] = *(const bf16x8*)(pw + (ks + 4) * 512);
                const int base = (2 * ks + lh) * 512 + (lane & 31) * 8 + nff * 256;
                bf16x8 bhv = *(const bf16x8*)(sH + base);
                bf16x8 blv = *(const bf16x8*)(sL + base);
                fh = MFMA(wk, bhv, fh, 0, 0, 0);
                fl = MFMA(wk, blv, fl, 0, 0, 0);
            }
            if (r >= rlo && r < rhi) {
                const int orow = rowidx[row0 + r];
                float* op = out + (size_t)orow * STYLE + of * 32 + lh * 4;
                const float* bop = bo + d * STYLE + of * 32 + lh * 4;
#pragma unroll
                for (int q = 0; q < 4; ++q) {
                    float4 v;
                    v.x = fh[q * 4 + 0] + fl[q * 4 + 0] + bop[q * 8 + 0];
                    v.y = fh[q * 4 + 1] + fl[q * 4 + 1] + bop[q * 8 + 1];
                    v.z = fh[q * 4 + 2] + fl[q * 4 + 2] + bop[q * 8 + 2];
                    v.w = fh[q * 4 + 3] + fl[q * 4 + 3] + bop[q * 8 + 3];
                    *(float4*)(op + q * 8) = v;
                }
            }
        }
    }
}

// ---------------- launch ----------------

extern "C" void kernel_launch(void* const* d_in, const int* in_sizes, int n_in,
                              void* d_out, int out_size, void* d_ws, size_t ws_size,
                              hipStream_t stream) {
    const float* z   = (const float*)d_in[0];
    const int*   y   = (const int*)d_in[1];
    const float* W0  = (const float*)d_in[2];
    const float* b0  = (const float*)d_in[3];
    const float* W1  = (const float*)d_in[4];
    const float* b1  = (const float*)d_in[5];
    const float* W2  = (const float*)d_in[6];
    const float* b2  = (const float*)d_in[7];
    const float* W3  = (const float*)d_in[8];
    const float* b3  = (const float*)d_in[9];
    const float* Wu1 = (const float*)d_in[10];
    const float* bu1 = (const float*)d_in[11];
    const float* Wu2 = (const float*)d_in[12];
    const float* bu2 = (const float*)d_in[13];
    const float* Wu3 = (const float*)d_in[14];
    const float* bu3 = (const float*)d_in[15];
    const float* Wo  = (const float*)d_in[16];
    const float* bo  = (const float*)d_in[17];
    float* out = (float*)d_out;

    short* Wp   = (short*)d_ws;                      // 33 * 262144 shorts (16.5 MB)
    short* W0p  = Wp + (size_t)33 * 262144;          // 8192 shorts
    short* WoP  = W0p + 8192;                        // 10 * 32768 shorts
    int* rowidx  = (int*)(WoP + (size_t)10 * 32768); // NB ints
    int* offsets = rowidx + NB;                      // NDOM+1 ints

    k_sort<<<1, 1024, 0, stream>>>(y, offsets, rowidx);
    k_prep<<<539, 256, 0, stream>>>(W1, W2, W3, Wu1, Wu2, Wu3, W0, Wo, Wp, W0p, WoP);
    k_fused<<<NWIN, 512, 0, stream>>>(z, rowidx, offsets, Wp, W0p, WoP,
                                      b0, b1, b2, b3, bu1, bu2, bu3, bo, out);
}